// Round 5
// baseline (2863.602 us; speedup 1.0000x reference)
//
#include <hip/hip_runtime.h>
#include <hip/hip_bf16.h>

#define N_NODES 100000
#define N_EDGES 3200000
#define D 128

typedef unsigned short u16;

// sort parameters (round-3 proven)
#define BKT_W 512                 // dst nodes per bucket
#define NBKT 196                  // ceil(100000/512)
#define NSH 8                     // shards per bucket (spreads atomic contention)
#define CAPS 2304                 // capacity per (bucket,shard); mean ~2064, +5.3 sigma
#define EPB 5120                  // edges per pass-1 block
#define P1B 625                   // pass-1 blocks (625*5120 = 3.2M exactly)
#define EPT 20                    // edges per thread (5120/256)

#define P2T 512                   // p2_deg threads
#define CW_BLOCKS 4               // w-convert tail blocks (2048/512)

#define AQ_T 512                  // agg3 threads (8 waves)
#define NQ 4                      // col quarters (32 cols = 64B each)
#define APAD 33                   // accum row pitch (+1 pad: bank = (dl+2w)%32)

typedef __attribute__((ext_vector_type(8))) short bf16x8;
typedef __attribute__((ext_vector_type(4))) float f32x4;

__device__ __forceinline__ float bf2f(u16 u) {
    union { unsigned i; float f; } a; a.i = ((unsigned)u) << 16; return a.f;
}
__device__ __forceinline__ float asf(unsigned u) {
    union { unsigned i; float f; } a; a.i = u; return a.f;
}
__device__ __forceinline__ u16 f2bf(float f) {
    __hip_bfloat16 b = __float2bfloat16(f);
    return *(u16*)&b;
}

// ---- pass 1: LDS multisplit into 196 buckets, sharded append (round-3 proven) ----
__global__ __launch_bounds__(256) void p1_multisplit(const int* __restrict__ ei,
                                                     int* __restrict__ bcnt,
                                                     unsigned* __restrict__ bbuf) {
    __shared__ unsigned s1[EPB];
    __shared__ unsigned s2[EPB];
    __shared__ int hist[NBKT], lbase[NBKT], cur[NBKT], gbase[NBKT];
    __shared__ int wsum4[4], wbase4[4];
    int t = threadIdx.x, blk = blockIdx.x;
    int sh = blk & (NSH - 1);
    int e0 = blk * EPB;
    if (t < NBKT) hist[t] = 0;
    __syncthreads();

    unsigned char bk[EPT];
#pragma unroll
    for (int k = 0; k < EPT; ++k) {
        int i = k * 256 + t;
        int s = ei[e0 + i];
        int d = ei[N_EDGES + e0 + i];
        unsigned bkt = (unsigned)d >> 9;
        bk[k] = (unsigned char)bkt;
        s1[i] = ((unsigned)s << 9) | ((unsigned)d & 511u);
        atomicAdd(&hist[bkt], 1);
    }
    __syncthreads();

    if (t < NBKT) gbase[t] = atomicAdd(&bcnt[t * NSH + sh], hist[t]);

    // exclusive prefix over hist[0..195] via per-wave shfl scan + wave-sum combine
    int lane = t & 63, wv = t >> 6;
    int hv = (t < NBKT) ? hist[t] : 0;
    int pre = hv;
#pragma unroll
    for (int o = 1; o < 64; o <<= 1) {
        int u = __shfl_up(pre, o);
        if (lane >= o) pre += u;
    }
    if (lane == 63) wsum4[wv] = pre;
    __syncthreads();
    if (t == 0) {
        int b = 0;
#pragma unroll
        for (int k = 0; k < 4; ++k) { wbase4[k] = b; b += wsum4[k]; }
    }
    __syncthreads();
    if (t < NBKT) { int ex = wbase4[wv] + pre - hv; lbase[t] = ex; cur[t] = ex; }
    __syncthreads();

#pragma unroll
    for (int k = 0; k < EPT; ++k) {
        int i = k * 256 + t;
        int p = atomicAdd(&cur[bk[k]], 1);
        s2[p] = s1[i];
    }
    __syncthreads();

    for (int bkt = wv; bkt < NBKT; bkt += 4) {
        int n = hist[bkt], lb = lbase[bkt], gb = gbase[bkt];
        unsigned* dst = bbuf + ((size_t)bkt * NSH + sh) * CAPS;
        for (int j = lane; j < n; j += 64) {
            int p = gb + j;
            if (p < CAPS) dst[p] = s2[lb + j];
        }
    }
}

// ---- pass 2 (light): per-bucket degree histogram -> dinv only.
//      No placement pass, no sorted write, no scan. Tail converts W. ----
__global__ __launch_bounds__(P2T) void p2_deg(const unsigned* __restrict__ bbuf,
                                              const int* __restrict__ bcnt,
                                              float* __restrict__ dinv_g,
                                              const float* __restrict__ w,
                                              u16* __restrict__ wbf) {
    __shared__ int hist[BKT_W];
    __shared__ int shcnt[NSH];
    int b = blockIdx.x, t = threadIdx.x;

    if (b >= NBKT) {
        int idx = (b - NBKT) * P2T + t;   // 0..2047
        const float4* wp = (const float4*)(w + (size_t)idx * 8);
        float4 a = wp[0], bb = wp[1];
        union { u16 h[8]; uint4 v; } o;
        o.h[0] = f2bf(a.x); o.h[1] = f2bf(a.y);
        o.h[2] = f2bf(a.z); o.h[3] = f2bf(a.w);
        o.h[4] = f2bf(bb.x); o.h[5] = f2bf(bb.y);
        o.h[6] = f2bf(bb.z); o.h[7] = f2bf(bb.w);
        ((uint4*)wbf)[idx] = o.v;
        return;
    }

    if (t < NSH) { int m = bcnt[b * NSH + t]; shcnt[t] = m > CAPS ? CAPS : m; }
    hist[t] = 0;                          // P2T == BKT_W
    __syncthreads();

    for (int sh = 0; sh < NSH; ++sh) {
        int m = shcnt[sh];
        const unsigned* p = bbuf + ((size_t)b * NSH + sh) * CAPS;
        for (int i = t; i < m; i += P2T) atomicAdd(&hist[p[i] & 511u], 1);
    }
    __syncthreads();

    int node = b * BKT_W + t;
    if (node < N_NODES) dinv_g[node] = rsqrtf((float)(hist[t] + 1));
}

// ---- GEMM: h[n] = dinv[n] * bf16(x[n] @ W^T), row-major (round-1 proven) ----
__global__ __launch_bounds__(256) void gemm_h(const float* __restrict__ x,
                                              const u16* __restrict__ wbf,
                                              const float* __restrict__ dinv,
                                              u16* __restrict__ h) {
    int t = threadIdx.x;
    int wave = t >> 6, lane = t & 63;
    int n0 = blockIdx.x * 64 + wave * 16;
    int lrow = lane & 15;
    int quad = lane >> 4;

    int arow = n0 + lrow;
    const float* ap = x + (size_t)(arow < N_NODES ? arow : 0) * D;
    bf16x8 afrag[4];
#pragma unroll
    for (int kt = 0; kt < 4; ++kt) {
        int k0 = kt * 32 + quad * 8;
        f32x4 x0 = *(const f32x4*)(ap + k0);
        f32x4 x1 = *(const f32x4*)(ap + k0 + 4);
        bf16x8 a;
        a[0] = (short)f2bf(x0.x); a[1] = (short)f2bf(x0.y);
        a[2] = (short)f2bf(x0.z); a[3] = (short)f2bf(x0.w);
        a[4] = (short)f2bf(x1.x); a[5] = (short)f2bf(x1.y);
        a[6] = (short)f2bf(x1.z); a[7] = (short)f2bf(x1.w);
        afrag[kt] = a;
    }

    float dsc[4];
#pragma unroll
    for (int i = 0; i < 4; ++i) {
        int n = n0 + quad * 4 + i;
        dsc[i] = (n < N_NODES) ? dinv[n] : 0.f;
    }

#pragma unroll
    for (int jt = 0; jt < 8; ++jt) {
        int j0 = jt * 16;
        f32x4 acc = {0.f, 0.f, 0.f, 0.f};
#pragma unroll
        for (int kt = 0; kt < 4; ++kt) {
            int k0 = kt * 32 + quad * 8;
            bf16x8 b = *(const bf16x8*)(wbf + (size_t)(j0 + lrow) * D + k0);
            acc = __builtin_amdgcn_mfma_f32_16x16x32_bf16(afrag[kt], b, acc, 0, 0, 0);
        }
#pragma unroll
        for (int i = 0; i < 4; ++i) {
            int n = n0 + quad * 4 + i;
            if (n < N_NODES) h[(size_t)n * D + j0 + lrow] = f2bf(acc[i] * dsc[i]);
        }
    }
}

// ---- agg3: bucket-driven LDS-accumulate aggregate.
// Block = (bucket b, col-quarter q). LDS fp32 accum [512][APAD] seeded with the
// self-loop h quarter; reads unsorted (src<<9|dlocal) straight from bbuf;
// each wave-instr gathers 4 edges x 64B quarter-rows (full lines, 8 in flight);
// ds_add_f32 fire-and-forget into accum. Writeout: *dinv[dst] + bias. ----
__global__ __launch_bounds__(AQ_T) void agg3(const u16* __restrict__ h,
                                             const float* __restrict__ dinv,
                                             const int* __restrict__ bcnt,
                                             const unsigned* __restrict__ bbuf,
                                             const float* __restrict__ bias,
                                             float* __restrict__ out) {
    __shared__ float accum[BKT_W * APAD];
    __shared__ int shcnt[NSH];
    int blk = blockIdx.x;
    int b = blk >> 2, q = blk & 3;
    int t = threadIdx.x;
    const unsigned* h32 = (const unsigned*)h;

    if (t < NSH) { int m = bcnt[b * NSH + t]; shcnt[t] = m > CAPS ? CAPS : m; }

    // seed accum with self-loop quarter (4 nodes x 16 words per wave-instr)
    for (int idx = t; idx < BKT_W * 16; idx += AQ_T) {
        int dl = idx >> 4, wd = idx & 15;
        int node = b * BKT_W + dl;
        unsigned u = (node < N_NODES) ? h32[(size_t)node * 64 + q * 16 + wd] : 0u;
        accum[dl * APAD + 2 * wd]     = asf(u << 16);
        accum[dl * APAD + 2 * wd + 1] = asf(u & 0xffff0000u);
    }
    __syncthreads();

    int wv = t >> 6, lane = t & 63;
    int eslot = lane >> 4;            // edge 0..3 within group
    int wd = lane & 15;               // u32 word within 64B quarter row

    for (int sh = 0; sh < NSH; ++sh) {
        int m = shcnt[sh];
        const unsigned* base = bbuf + ((size_t)b * NSH + sh) * CAPS;
        for (int i0 = wv * 32; i0 < m; i0 += 8 * 32) {
            unsigned ew[8];
#pragma unroll
            for (int g = 0; g < 8; ++g) {
                int e = i0 + g * 4 + eslot;
                ew[g] = (e < m) ? base[e] : 0xFFFFFFFFu;
            }
            unsigned hv[8];
#pragma unroll
            for (int g = 0; g < 8; ++g) {
                unsigned w = ew[g];
                hv[g] = (w != 0xFFFFFFFFu)
                      ? h32[(size_t)(w >> 9) * 64 + q * 16 + wd] : 0u;
            }
#pragma unroll
            for (int g = 0; g < 8; ++g) {
                int dl = (ew[g] != 0xFFFFFFFFu) ? (int)(ew[g] & 511u) : 0;
                atomicAdd(&accum[dl * APAD + 2 * wd],     asf(hv[g] << 16));
                atomicAdd(&accum[dl * APAD + 2 * wd + 1], asf(hv[g] & 0xffff0000u));
            }
        }
    }
    __syncthreads();

    // writeout: out[node][q*32+col] = accum * dinv[node] + bias[q*32+col]
    for (int idx = t; idx < BKT_W * 32; idx += AQ_T) {
        int dl = idx >> 5, col = idx & 31;
        int node = b * BKT_W + dl;
        if (node < N_NODES) {
            out[(size_t)node * D + q * 32 + col] =
                accum[dl * APAD + col] * dinv[node] + bias[q * 32 + col];
        }
    }
    if (blk == 0 && t == 0) out[(size_t)N_NODES * D] = 0.f;  // tuple scalar
}

extern "C" void kernel_launch(void* const* d_in, const int* in_sizes, int n_in,
                              void* d_out, int out_size, void* d_ws, size_t ws_size,
                              hipStream_t stream) {
    const float* x = (const float*)d_in[0];
    const int* ei = (const int*)d_in[1];
    const float* w = (const float*)d_in[2];
    const float* bias = (const float*)d_in[3];
    float* out = (float*)d_out;

    char* ws = (char*)d_ws;
    size_t o = 0;
    auto alloc = [&](size_t bytes) -> char* {
        char* p = ws + o;
        o = (o + bytes + 511) & ~(size_t)511;
        return p;
    };
    u16* h = (u16*)alloc((size_t)N_NODES * D * 2);              // 25.6 MB
    unsigned* bbuf = (unsigned*)alloc((size_t)NBKT * NSH * CAPS * 4); // 14.45 MB (live thru agg3)
    float* dinv = (float*)alloc((size_t)N_NODES * 4);           // 0.4 MB
    int* bcnt = (int*)alloc((size_t)NBKT * NSH * 4);            // 6.3 KB
    u16* wbf = (u16*)alloc((size_t)D * D * 2);                  // 32 KB
    // total ws: ~40.5 MB (same size class)

    hipMemsetAsync(bcnt, 0, (size_t)NBKT * NSH * 4, stream);

    p1_multisplit<<<P1B, 256, 0, stream>>>(ei, bcnt, bbuf);
    p2_deg<<<NBKT + CW_BLOCKS, P2T, 0, stream>>>(bbuf, bcnt, dinv, w, wbf);
    gemm_h<<<(N_NODES + 63) / 64, 256, 0, stream>>>(x, wbf, dinv, h);
    agg3<<<NBKT * NQ, AQ_T, 0, stream>>>(h, dinv, bcnt, bbuf, bias, out);
}

// Round 6
// 294.360 us; speedup vs baseline: 9.7282x; 9.7282x over previous
//
#include <hip/hip_runtime.h>
#include <hip/hip_bf16.h>

#define N_NODES 100000
#define N_EDGES 3200000
#define D 128

typedef unsigned short u16;

// sort parameters (round-3 proven)
#define BKT_W 512                 // dst nodes per bucket
#define NBKT 196                  // ceil(100000/512)
#define NSH 8                     // shards per bucket (spreads atomic contention)
#define CAPS 2304                 // capacity per (bucket,shard); mean ~2064, +5.3 sigma
#define CAPB (NSH * CAPS)         // 18432 per bucket
#define EPB 5120                  // edges per pass-1 block
#define P1B 625                   // pass-1 blocks (625*5120 = 3.2M exactly)
#define EPT 20                    // edges per thread (5120/256)
#define GEMM_B 1563               // gemm tail blocks on p1 grid: ceil(100000/64)

typedef __attribute__((ext_vector_type(8))) short bf16x8;
typedef __attribute__((ext_vector_type(4))) float f32x4;

__device__ __forceinline__ float bf2f(u16 u) {
    union { unsigned i; float f; } a; a.i = ((unsigned)u) << 16; return a.f;
}
__device__ __forceinline__ float asf(unsigned u) {
    union { unsigned i; float f; } a; a.i = u; return a.f;
}
__device__ __forceinline__ u16 f2bf(float f) {
    __hip_bfloat16 b = __float2bfloat16(f);
    return *(u16*)&b;
}

// ---- W -> bf16 (tiny, runs first so fused gemm blocks can read wbf) ----
__global__ __launch_bounds__(256) void wconv(const float* __restrict__ w,
                                             u16* __restrict__ wbf) {
    int idx = blockIdx.x * 256 + threadIdx.x;   // 0..2047
    const float4* wp = (const float4*)(w + (size_t)idx * 8);
    float4 a = wp[0], bb = wp[1];
    union { u16 h[8]; uint4 v; } o;
    o.h[0] = f2bf(a.x); o.h[1] = f2bf(a.y);
    o.h[2] = f2bf(a.z); o.h[3] = f2bf(a.w);
    o.h[4] = f2bf(bb.x); o.h[5] = f2bf(bb.y);
    o.h[6] = f2bf(bb.z); o.h[7] = f2bf(bb.w);
    ((uint4*)wbf)[idx] = o.v;
}

// ---- p1 (blocks [0,P1B)): LDS multisplit into 196 buckets, sharded append.
//      Tail blocks [P1B, P1B+GEMM_B): h[n] = bf16(x[n] @ W^T)  (NO dinv — applied
//      at aggregate). Complementary pipes: p1 is LDS/atomic-bound, gemm is
//      MFMA/stream-bound -> gemm hides under p1. ----
__global__ __launch_bounds__(256) void p1_gemm(const int* __restrict__ ei,
                                               int* __restrict__ bcnt,
                                               unsigned* __restrict__ bbuf,
                                               const float* __restrict__ x,
                                               const u16* __restrict__ wbf,
                                               u16* __restrict__ h) {
    __shared__ unsigned s1[EPB];
    __shared__ unsigned s2[EPB];
    __shared__ int hist[NBKT], lbase[NBKT], cur[NBKT], gbase[NBKT];
    __shared__ int wsum4[4], wbase4[4];
    int t = threadIdx.x, blk = blockIdx.x;

    if (blk >= P1B) {
        // ---------------- GEMM tail ----------------
        int wave = t >> 6, lane = t & 63;
        int n0 = (blk - P1B) * 64 + wave * 16;
        int lrow = lane & 15;
        int quad = lane >> 4;

        int arow = n0 + lrow;
        const float* ap = x + (size_t)(arow < N_NODES ? arow : 0) * D;
        bf16x8 afrag[4];
#pragma unroll
        for (int kt = 0; kt < 4; ++kt) {
            int k0 = kt * 32 + quad * 8;
            f32x4 x0 = *(const f32x4*)(ap + k0);
            f32x4 x1 = *(const f32x4*)(ap + k0 + 4);
            bf16x8 a;
            a[0] = (short)f2bf(x0.x); a[1] = (short)f2bf(x0.y);
            a[2] = (short)f2bf(x0.z); a[3] = (short)f2bf(x0.w);
            a[4] = (short)f2bf(x1.x); a[5] = (short)f2bf(x1.y);
            a[6] = (short)f2bf(x1.z); a[7] = (short)f2bf(x1.w);
            afrag[kt] = a;
        }

#pragma unroll
        for (int jt = 0; jt < 8; ++jt) {
            int j0 = jt * 16;
            f32x4 acc = {0.f, 0.f, 0.f, 0.f};
#pragma unroll
            for (int kt = 0; kt < 4; ++kt) {
                int k0 = kt * 32 + quad * 8;
                bf16x8 b = *(const bf16x8*)(wbf + (size_t)(j0 + lrow) * D + k0);
                acc = __builtin_amdgcn_mfma_f32_16x16x32_bf16(afrag[kt], b, acc, 0, 0, 0);
            }
#pragma unroll
            for (int i = 0; i < 4; ++i) {
                int n = n0 + quad * 4 + i;
                if (n < N_NODES) h[(size_t)n * D + j0 + lrow] = f2bf(acc[i]);
            }
        }
        return;
    }

    // ---------------- p1 multisplit ----------------
    int sh = blk & (NSH - 1);
    int e0 = blk * EPB;
    if (t < NBKT) hist[t] = 0;
    __syncthreads();

    unsigned char bk[EPT];
#pragma unroll
    for (int k = 0; k < EPT; ++k) {
        int i = k * 256 + t;
        int s = ei[e0 + i];
        int d = ei[N_EDGES + e0 + i];
        unsigned bkt = (unsigned)d >> 9;
        bk[k] = (unsigned char)bkt;
        s1[i] = ((unsigned)s << 9) | ((unsigned)d & 511u);
        atomicAdd(&hist[bkt], 1);
    }
    __syncthreads();

    if (t < NBKT) gbase[t] = atomicAdd(&bcnt[t * NSH + sh], hist[t]);

    // exclusive prefix over hist[0..195] via per-wave shfl scan + wave-sum combine
    int lane = t & 63, wv = t >> 6;
    int hv = (t < NBKT) ? hist[t] : 0;
    int pre = hv;
#pragma unroll
    for (int o = 1; o < 64; o <<= 1) {
        int u = __shfl_up(pre, o);
        if (lane >= o) pre += u;
    }
    if (lane == 63) wsum4[wv] = pre;
    __syncthreads();
    if (t == 0) {
        int b = 0;
#pragma unroll
        for (int k = 0; k < 4; ++k) { wbase4[k] = b; b += wsum4[k]; }
    }
    __syncthreads();
    if (t < NBKT) { int ex = wbase4[wv] + pre - hv; lbase[t] = ex; cur[t] = ex; }
    __syncthreads();

#pragma unroll
    for (int k = 0; k < EPT; ++k) {
        int i = k * 256 + t;
        int p = atomicAdd(&cur[bk[k]], 1);
        s2[p] = s1[i];
    }
    __syncthreads();

    for (int bkt = wv; bkt < NBKT; bkt += 4) {
        int n = hist[bkt], lb = lbase[bkt], gb = gbase[bkt];
        unsigned* dst = bbuf + ((size_t)bkt * NSH + sh) * CAPS;
        for (int j = lane; j < n; j += 64) {
            int p = gb + j;
            if (p < CAPS) dst[p] = s2[lb + j];
        }
    }
}

// ---- pass 2: per-bucket counting sort; bucket staged in LDS ONCE (single
//      global read); sorted written IN PLACE over the bucket's bbuf region
//      (safe: fully staged before overwrite, per-block disjoint). ----
__global__ __launch_bounds__(1024) void p2_localsort(unsigned* __restrict__ bbuf,
                                                     const int* __restrict__ bcnt,
                                                     int* __restrict__ beg_g,
                                                     int* __restrict__ cnt_g,
                                                     float* __restrict__ dinv_g) {
    __shared__ unsigned stage[CAPB];      // 73.7 KB
    __shared__ int hist[BKT_W], cur[BKT_W], shcnt[NSH];
    __shared__ int wsum[8], wbase[8];
    int b = blockIdx.x, t = threadIdx.x;

    if (t < NSH) { int m = bcnt[b * NSH + t]; shcnt[t] = m > CAPS ? CAPS : m; }
    if (t < BKT_W) hist[t] = 0;
    __syncthreads();

    // stage + histogram in one pass
    for (int sh = 0; sh < NSH; ++sh) {
        int m = shcnt[sh];
        const unsigned* p = bbuf + ((size_t)b * NSH + sh) * CAPS;
        for (int i = t; i < m; i += 1024) {
            unsigned w = p[i];
            stage[sh * CAPS + i] = w;
            atomicAdd(&hist[w & 511u], 1);
        }
    }
    __syncthreads();

    // exclusive prefix over hist[0..511]: waves 0-7 shfl-scan, wave 0 combines
    int lane = t & 63, wv = t >> 6;
    int hv = (t < BKT_W) ? hist[t] : 0;
    int pre = hv;
#pragma unroll
    for (int o = 1; o < 64; o <<= 1) {
        int u = __shfl_up(pre, o);
        if (lane >= o) pre += u;
    }
    if (wv < 8 && lane == 63) wsum[wv] = pre;
    __syncthreads();
    if (wv == 0) {
        int v = (lane < 8) ? wsum[lane] : 0;
        int pp = v;
#pragma unroll
        for (int o = 1; o < 8; o <<= 1) {
            int u = __shfl_up(pp, o);
            if (lane >= o) pp += u;
        }
        if (lane < 8) wbase[lane] = pp - v;
    }
    __syncthreads();
    int ex = 0;
    if (t < BKT_W) { ex = wbase[wv] + pre - hv; cur[t] = ex; }

    if (t < BKT_W) {
        int node = b * BKT_W + t;
        if (node < N_NODES) {
            cnt_g[node] = hv;
            beg_g[node] = b * CAPB + ex;
            dinv_g[node] = rsqrtf((float)(hv + 1));
        }
    }
    __syncthreads();

    // placement: LDS stage -> global (in place over this bucket's bbuf region)
    int* dst = (int*)(bbuf + (size_t)b * CAPB);
    for (int sh = 0; sh < NSH; ++sh) {
        int m = shcnt[sh];
        for (int i = t; i < m; i += 1024) {
            unsigned ww = stage[sh * CAPS + i];
            int pp = atomicAdd(&cur[ww & 511u], 1);
            dst[pp] = (int)(ww >> 9);
        }
    }
}

// ---- aggregate: out[n] = dinv[n] * (dinv[n]*h[n] + sum_s dinv[s]*h[s]) + bias.
// Round-3 proven structure; dinv[s] folded here (broadcast load + FMA) instead
// of at gemm time, which let the gemm hide under p1. ----
__global__ __launch_bounds__(256) void aggregate_h2(const u16* __restrict__ h,
                                                    const float* __restrict__ dinv,
                                                    const int* __restrict__ beg_g,
                                                    const int* __restrict__ cnt_g,
                                                    const int* __restrict__ sorted_src,
                                                    const float* __restrict__ bias,
                                                    float* __restrict__ out) {
    int w = threadIdx.x >> 6;
    int l = threadIdx.x & 63;
    int n = blockIdx.x * 4 + w;          // grid 25000 * 4 = 100000 exactly
    const unsigned* h32 = (const unsigned*)h;

    float dn = dinv[n];
    unsigned us = h32[(size_t)n * 64 + l];       // self-loop: dinv[n]*h[n]
    float acc0 = dn * asf(us << 16);
    float acc1 = dn * asf(us & 0xffff0000u);

    int c = __builtin_amdgcn_readfirstlane(cnt_g[n]);
    int beg = __builtin_amdgcn_readfirstlane(beg_g[n]);
    const int* sp = sorted_src + beg;

    int i = 0;
    for (; i + 16 <= c; i += 16) {
        int s[16];
#pragma unroll
        for (int j = 0; j < 16; ++j) s[j] = sp[i + j];
        float dv[16];
#pragma unroll
        for (int j = 0; j < 16; ++j) dv[j] = dinv[s[j]];
        unsigned u[16];
#pragma unroll
        for (int j = 0; j < 16; ++j) u[j] = h32[(size_t)s[j] * 64 + l];
#pragma unroll
        for (int j = 0; j < 16; ++j) {
            acc0 += dv[j] * asf(u[j] << 16);
            acc1 += dv[j] * asf(u[j] & 0xffff0000u);
        }
    }
    for (; i + 4 <= c; i += 4) {
        int s0 = sp[i], s1 = sp[i + 1], s2 = sp[i + 2], s3 = sp[i + 3];
        float d0 = dinv[s0], d1 = dinv[s1], d2 = dinv[s2], d3 = dinv[s3];
        unsigned u0 = h32[(size_t)s0 * 64 + l];
        unsigned u1 = h32[(size_t)s1 * 64 + l];
        unsigned u2 = h32[(size_t)s2 * 64 + l];
        unsigned u3 = h32[(size_t)s3 * 64 + l];
        acc0 += d0 * asf(u0 << 16); acc1 += d0 * asf(u0 & 0xffff0000u);
        acc0 += d1 * asf(u1 << 16); acc1 += d1 * asf(u1 & 0xffff0000u);
        acc0 += d2 * asf(u2 << 16); acc1 += d2 * asf(u2 & 0xffff0000u);
        acc0 += d3 * asf(u3 << 16); acc1 += d3 * asf(u3 & 0xffff0000u);
    }
    for (; i < c; ++i) {
        int s = sp[i];
        float dv = dinv[s];
        unsigned u = h32[(size_t)s * 64 + l];
        acc0 += dv * asf(u << 16); acc1 += dv * asf(u & 0xffff0000u);
    }

    float2 bs = ((const float2*)bias)[l];
    float2 o;
    o.x = acc0 * dn + bs.x;
    o.y = acc1 * dn + bs.y;
    ((float2*)out)[(size_t)n * 64 + l] = o;

    if (blockIdx.x == 0 && threadIdx.x == 0) out[(size_t)N_NODES * D] = 0.f;  // tuple scalar
}

extern "C" void kernel_launch(void* const* d_in, const int* in_sizes, int n_in,
                              void* d_out, int out_size, void* d_ws, size_t ws_size,
                              hipStream_t stream) {
    const float* x = (const float*)d_in[0];
    const int* ei = (const int*)d_in[1];
    const float* w = (const float*)d_in[2];
    const float* bias = (const float*)d_in[3];
    float* out = (float*)d_out;

    char* ws = (char*)d_ws;
    size_t o = 0;
    auto alloc = [&](size_t bytes) -> char* {
        char* p = ws + o;
        o = (o + bytes + 511) & ~(size_t)511;
        return p;
    };
    u16* h = (u16*)alloc((size_t)N_NODES * D * 2);              // 25.6 MB
    unsigned* bbuf = (unsigned*)alloc((size_t)NBKT * CAPB * 4); // 14.45 MB; becomes sorted in p2
    int* sorted = (int*)bbuf;                                    // alias (in-place per bucket)
    int* cnt = (int*)alloc((size_t)N_NODES * 4);                // 0.4 MB
    int* beg = (int*)alloc((size_t)N_NODES * 4);                // 0.4 MB
    float* dinv = (float*)alloc((size_t)N_NODES * 4);           // 0.4 MB
    int* bcnt = (int*)alloc((size_t)NBKT * NSH * 4);            // 6.3 KB
    u16* wbf = (u16*)alloc((size_t)D * D * 2);                  // 32 KB
    // total ws: ~41.3 MB (proven size class)

    hipMemsetAsync(bcnt, 0, (size_t)NBKT * NSH * 4, stream);

    wconv<<<8, 256, 0, stream>>>(w, wbf);
    p1_gemm<<<P1B + GEMM_B, 256, 0, stream>>>(ei, bcnt, bbuf, x, wbf, h);
    p2_localsort<<<NBKT, 1024, 0, stream>>>(bbuf, bcnt, beg, cnt, dinv);
    aggregate_h2<<<N_NODES / 4, 256, 0, stream>>>(h, dinv, beg, cnt, sorted, bias, out);
}

// Round 7
// 290.584 us; speedup vs baseline: 9.8546x; 1.0130x over previous
//
#include <hip/hip_runtime.h>
#include <hip/hip_bf16.h>

#define N_NODES 100000
#define N_EDGES 3200000
#define D 128

typedef unsigned short u16;

// sort parameters (round-7: 250 buckets x 400 nodes = 100000 exactly)
#define BKT_W 400                 // dst nodes per bucket
#define NBKT 250                  // 100000/400
#define NSH 8                     // shards per bucket (spreads atomic contention)
#define CAPS 1856                 // capacity per (bucket,shard); mean ~1600, +5.9 sigma
#define CAPB (NSH * CAPS)         // 14848 per bucket
#define EPB 5120                  // edges per pass-1 block
#define P1B 625                   // pass-1 blocks (625*5120 = 3.2M exactly)
#define EPT 20                    // edges per thread (5120/256)
#define GEMM_B 1563               // gemm tail blocks on p1 grid: ceil(100000/64)

typedef __attribute__((ext_vector_type(8))) short bf16x8;
typedef __attribute__((ext_vector_type(4))) float f32x4;

__device__ __forceinline__ float bf2f(u16 u) {
    union { unsigned i; float f; } a; a.i = ((unsigned)u) << 16; return a.f;
}
__device__ __forceinline__ float asf(unsigned u) {
    union { unsigned i; float f; } a; a.i = u; return a.f;
}
__device__ __forceinline__ u16 f2bf(float f) {
    __hip_bfloat16 b = __float2bfloat16(f);
    return *(u16*)&b;
}

// ---- W -> bf16 (tiny, runs first so fused gemm blocks can read wbf) ----
__global__ __launch_bounds__(256) void wconv(const float* __restrict__ w,
                                             u16* __restrict__ wbf) {
    int idx = blockIdx.x * 256 + threadIdx.x;   // 0..2047
    const float4* wp = (const float4*)(w + (size_t)idx * 8);
    float4 a = wp[0], bb = wp[1];
    union { u16 h[8]; uint4 v; } o;
    o.h[0] = f2bf(a.x); o.h[1] = f2bf(a.y);
    o.h[2] = f2bf(a.z); o.h[3] = f2bf(a.w);
    o.h[4] = f2bf(bb.x); o.h[5] = f2bf(bb.y);
    o.h[6] = f2bf(bb.z); o.h[7] = f2bf(bb.w);
    ((uint4*)wbf)[idx] = o.v;
}

// ---- p1 (blocks [0,P1B)): LDS multisplit into 250 buckets, sharded append.
//      int4 edge loads (4 consecutive edges/thread): 10 global load instrs
//      per thread instead of 40.
//      Tail blocks [P1B, P1B+GEMM_B): h[n] = bf16(x[n] @ W^T) (NO dinv — applied
//      at aggregate). gemm hides under p1 on complementary pipes. ----
__global__ __launch_bounds__(256) void p1_gemm(const int* __restrict__ ei,
                                               int* __restrict__ bcnt,
                                               unsigned* __restrict__ bbuf,
                                               const float* __restrict__ x,
                                               const u16* __restrict__ wbf,
                                               u16* __restrict__ h) {
    __shared__ unsigned s1[EPB];
    __shared__ unsigned s2[EPB];
    __shared__ int hist[NBKT], lbase[NBKT], cur[NBKT], gbase[NBKT];
    __shared__ int wsum4[4], wbase4[4];
    int t = threadIdx.x, blk = blockIdx.x;

    if (blk >= P1B) {
        // ---------------- GEMM tail ----------------
        int wave = t >> 6, lane = t & 63;
        int n0 = (blk - P1B) * 64 + wave * 16;
        int lrow = lane & 15;
        int quad = lane >> 4;

        int arow = n0 + lrow;
        const float* ap = x + (size_t)(arow < N_NODES ? arow : 0) * D;
        bf16x8 afrag[4];
#pragma unroll
        for (int kt = 0; kt < 4; ++kt) {
            int k0 = kt * 32 + quad * 8;
            f32x4 x0 = *(const f32x4*)(ap + k0);
            f32x4 x1 = *(const f32x4*)(ap + k0 + 4);
            bf16x8 a;
            a[0] = (short)f2bf(x0.x); a[1] = (short)f2bf(x0.y);
            a[2] = (short)f2bf(x0.z); a[3] = (short)f2bf(x0.w);
            a[4] = (short)f2bf(x1.x); a[5] = (short)f2bf(x1.y);
            a[6] = (short)f2bf(x1.z); a[7] = (short)f2bf(x1.w);
            afrag[kt] = a;
        }

#pragma unroll
        for (int jt = 0; jt < 8; ++jt) {
            int j0 = jt * 16;
            f32x4 acc = {0.f, 0.f, 0.f, 0.f};
#pragma unroll
            for (int kt = 0; kt < 4; ++kt) {
                int k0 = kt * 32 + quad * 8;
                bf16x8 b = *(const bf16x8*)(wbf + (size_t)(j0 + lrow) * D + k0);
                acc = __builtin_amdgcn_mfma_f32_16x16x32_bf16(afrag[kt], b, acc, 0, 0, 0);
            }
#pragma unroll
            for (int i = 0; i < 4; ++i) {
                int n = n0 + quad * 4 + i;
                if (n < N_NODES) h[(size_t)n * D + j0 + lrow] = f2bf(acc[i]);
            }
        }
        return;
    }

    // ---------------- p1 multisplit ----------------
    int sh = blk & (NSH - 1);
    int e0 = blk * EPB;
    if (t < NBKT) hist[t] = 0;
    __syncthreads();

    unsigned char bk[EPT];
#pragma unroll
    for (int k = 0; k < 5; ++k) {
        int base = k * 1024 + t * 4;          // 4 consecutive edges
        int4 s4 = *(const int4*)(ei + e0 + base);
        int4 d4 = *(const int4*)(ei + N_EDGES + e0 + base);
        int ss[4] = {s4.x, s4.y, s4.z, s4.w};
        int dd[4] = {d4.x, d4.y, d4.z, d4.w};
#pragma unroll
        for (int j = 0; j < 4; ++j) {
            unsigned bkt = (unsigned)dd[j] / BKT_W;
            unsigned dl = (unsigned)dd[j] - bkt * BKT_W;
            bk[k * 4 + j] = (unsigned char)bkt;
            s1[base + j] = ((unsigned)ss[j] << 9) | dl;
            atomicAdd(&hist[bkt], 1);
        }
    }
    __syncthreads();

    if (t < NBKT) gbase[t] = atomicAdd(&bcnt[t * NSH + sh], hist[t]);

    // exclusive prefix over hist[0..249] via per-wave shfl scan + wave-sum combine
    int lane = t & 63, wv = t >> 6;
    int hv = (t < NBKT) ? hist[t] : 0;
    int pre = hv;
#pragma unroll
    for (int o = 1; o < 64; o <<= 1) {
        int u = __shfl_up(pre, o);
        if (lane >= o) pre += u;
    }
    if (lane == 63) wsum4[wv] = pre;
    __syncthreads();
    if (t == 0) {
        int b = 0;
#pragma unroll
        for (int k = 0; k < 4; ++k) { wbase4[k] = b; b += wsum4[k]; }
    }
    __syncthreads();
    if (t < NBKT) { int ex = wbase4[wv] + pre - hv; lbase[t] = ex; cur[t] = ex; }
    __syncthreads();

#pragma unroll
    for (int k = 0; k < 5; ++k) {
        int base = k * 1024 + t * 4;
#pragma unroll
        for (int j = 0; j < 4; ++j) {
            int p = atomicAdd(&cur[bk[k * 4 + j]], 1);
            s2[p] = s1[base + j];
        }
    }
    __syncthreads();

    for (int bkt = wv; bkt < NBKT; bkt += 4) {
        int n = hist[bkt], lb = lbase[bkt], gb = gbase[bkt];
        unsigned* dst = bbuf + ((size_t)bkt * NSH + sh) * CAPS;
        for (int j = lane; j < n; j += 64) {
            int p = gb + j;
            if (p < CAPS) dst[p] = s2[lb + j];
        }
    }
}

// ---- pass 2: per-bucket counting sort; bucket staged in LDS ONCE (single
//      global read); sorted written IN PLACE over the bucket's bbuf region
//      (safe: fully staged before overwrite, per-block disjoint).
//      250 blocks -> 98% CU coverage (was 196 = 77%); stage 59.4 KB. ----
__global__ __launch_bounds__(1024) void p2_localsort(unsigned* __restrict__ bbuf,
                                                     const int* __restrict__ bcnt,
                                                     int* __restrict__ beg_g,
                                                     int* __restrict__ cnt_g,
                                                     float* __restrict__ dinv_g) {
    __shared__ unsigned stage[CAPB];      // 59.4 KB
    __shared__ int hist[BKT_W], cur[BKT_W], shcnt[NSH];
    __shared__ int wsum[8], wbase[8];
    int b = blockIdx.x, t = threadIdx.x;

    if (t < NSH) { int m = bcnt[b * NSH + t]; shcnt[t] = m > CAPS ? CAPS : m; }
    if (t < BKT_W) hist[t] = 0;
    __syncthreads();

    // stage + histogram in one pass
    for (int sh = 0; sh < NSH; ++sh) {
        int m = shcnt[sh];
        const unsigned* p = bbuf + ((size_t)b * NSH + sh) * CAPS;
        for (int i = t; i < m; i += 1024) {
            unsigned w = p[i];
            stage[sh * CAPS + i] = w;
            atomicAdd(&hist[w & 511u], 1);
        }
    }
    __syncthreads();

    // exclusive prefix over hist[0..399]: waves 0-6 shfl-scan, wave 0 combines
    int lane = t & 63, wv = t >> 6;
    int hv = (t < BKT_W) ? hist[t] : 0;
    int pre = hv;
#pragma unroll
    for (int o = 1; o < 64; o <<= 1) {
        int u = __shfl_up(pre, o);
        if (lane >= o) pre += u;
    }
    if (wv < 8 && lane == 63) wsum[wv] = pre;
    __syncthreads();
    if (wv == 0) {
        int v = (lane < 8) ? wsum[lane] : 0;
        int pp = v;
#pragma unroll
        for (int o = 1; o < 8; o <<= 1) {
            int u = __shfl_up(pp, o);
            if (lane >= o) pp += u;
        }
        if (lane < 8) wbase[lane] = pp - v;
    }
    __syncthreads();
    int ex = 0;
    if (t < BKT_W) { ex = wbase[wv] + pre - hv; cur[t] = ex; }

    if (t < BKT_W) {
        int node = b * BKT_W + t;             // 250*400 = 100000 exact
        cnt_g[node] = hv;
        beg_g[node] = b * CAPB + ex;
        dinv_g[node] = rsqrtf((float)(hv + 1));
    }
    __syncthreads();

    // placement: LDS stage -> global (in place over this bucket's bbuf region)
    int* dst = (int*)(bbuf + (size_t)b * CAPB);
    for (int sh = 0; sh < NSH; ++sh) {
        int m = shcnt[sh];
        for (int i = t; i < m; i += 1024) {
            unsigned ww = stage[sh * CAPS + i];
            int pp = atomicAdd(&cur[ww & 511u], 1);
            dst[pp] = (int)(ww >> 9);
        }
    }
}

// ---- aggregate: out[n] = dinv[n] * (dinv[n]*h[n] + sum_s dinv[s]*h[s]) + bias.
// Round-3 proven structure; dinv[s] folded here (L2-resident broadcast + FMA). ----
__global__ __launch_bounds__(256) void aggregate_h2(const u16* __restrict__ h,
                                                    const float* __restrict__ dinv,
                                                    const int* __restrict__ beg_g,
                                                    const int* __restrict__ cnt_g,
                                                    const int* __restrict__ sorted_src,
                                                    const float* __restrict__ bias,
                                                    float* __restrict__ out) {
    int w = threadIdx.x >> 6;
    int l = threadIdx.x & 63;
    int n = blockIdx.x * 4 + w;          // grid 25000 * 4 = 100000 exactly
    const unsigned* h32 = (const unsigned*)h;

    float dn = dinv[n];
    unsigned us = h32[(size_t)n * 64 + l];       // self-loop: dinv[n]*h[n]
    float acc0 = dn * asf(us << 16);
    float acc1 = dn * asf(us & 0xffff0000u);

    int c = __builtin_amdgcn_readfirstlane(cnt_g[n]);
    int beg = __builtin_amdgcn_readfirstlane(beg_g[n]);
    const int* sp = sorted_src + beg;

    int i = 0;
    for (; i + 16 <= c; i += 16) {
        int s[16];
#pragma unroll
        for (int j = 0; j < 16; ++j) s[j] = sp[i + j];
        float dv[16];
#pragma unroll
        for (int j = 0; j < 16; ++j) dv[j] = dinv[s[j]];
        unsigned u[16];
#pragma unroll
        for (int j = 0; j < 16; ++j) u[j] = h32[(size_t)s[j] * 64 + l];
#pragma unroll
        for (int j = 0; j < 16; ++j) {
            acc0 += dv[j] * asf(u[j] << 16);
            acc1 += dv[j] * asf(u[j] & 0xffff0000u);
        }
    }
    for (; i + 4 <= c; i += 4) {
        int s0 = sp[i], s1 = sp[i + 1], s2 = sp[i + 2], s3 = sp[i + 3];
        float d0 = dinv[s0], d1 = dinv[s1], d2 = dinv[s2], d3 = dinv[s3];
        unsigned u0 = h32[(size_t)s0 * 64 + l];
        unsigned u1 = h32[(size_t)s1 * 64 + l];
        unsigned u2 = h32[(size_t)s2 * 64 + l];
        unsigned u3 = h32[(size_t)s3 * 64 + l];
        acc0 += d0 * asf(u0 << 16); acc1 += d0 * asf(u0 & 0xffff0000u);
        acc0 += d1 * asf(u1 << 16); acc1 += d1 * asf(u1 & 0xffff0000u);
        acc0 += d2 * asf(u2 << 16); acc1 += d2 * asf(u2 & 0xffff0000u);
        acc0 += d3 * asf(u3 << 16); acc1 += d3 * asf(u3 & 0xffff0000u);
    }
    for (; i < c; ++i) {
        int s = sp[i];
        float dv = dinv[s];
        unsigned u = h32[(size_t)s * 64 + l];
        acc0 += dv * asf(u << 16); acc1 += dv * asf(u & 0xffff0000u);
    }

    float2 bs = ((const float2*)bias)[l];
    float2 o;
    o.x = acc0 * dn + bs.x;
    o.y = acc1 * dn + bs.y;
    ((float2*)out)[(size_t)n * 64 + l] = o;

    if (blockIdx.x == 0 && threadIdx.x == 0) out[(size_t)N_NODES * D] = 0.f;  // tuple scalar
}

extern "C" void kernel_launch(void* const* d_in, const int* in_sizes, int n_in,
                              void* d_out, int out_size, void* d_ws, size_t ws_size,
                              hipStream_t stream) {
    const float* x = (const float*)d_in[0];
    const int* ei = (const int*)d_in[1];
    const float* w = (const float*)d_in[2];
    const float* bias = (const float*)d_in[3];
    float* out = (float*)d_out;

    char* ws = (char*)d_ws;
    size_t o = 0;
    auto alloc = [&](size_t bytes) -> char* {
        char* p = ws + o;
        o = (o + bytes + 511) & ~(size_t)511;
        return p;
    };
    u16* h = (u16*)alloc((size_t)N_NODES * D * 2);              // 25.6 MB
    unsigned* bbuf = (unsigned*)alloc((size_t)NBKT * CAPB * 4); // 14.85 MB; becomes sorted in p2
    int* sorted = (int*)bbuf;                                    // alias (in-place per bucket)
    int* cnt = (int*)alloc((size_t)N_NODES * 4);                // 0.4 MB
    int* beg = (int*)alloc((size_t)N_NODES * 4);                // 0.4 MB
    float* dinv = (float*)alloc((size_t)N_NODES * 4);           // 0.4 MB
    int* bcnt = (int*)alloc((size_t)NBKT * NSH * 4);            // 8 KB
    u16* wbf = (u16*)alloc((size_t)D * D * 2);                  // 32 KB
    // total ws: ~41.7 MB (proven size class)

    hipMemsetAsync(bcnt, 0, (size_t)NBKT * NSH * 4, stream);

    wconv<<<8, 256, 0, stream>>>(w, wbf);
    p1_gemm<<<P1B + GEMM_B, 256, 0, stream>>>(ei, bcnt, bbuf, x, wbf, h);
    p2_localsort<<<NBKT, 1024, 0, stream>>>(bbuf, bcnt, beg, cnt, dinv);
    aggregate_h2<<<N_NODES / 4, 256, 0, stream>>>(h, dinv, beg, cnt, sorted, bias, out);
}